// Round 18
// baseline (463.342 us; speedup 1.0000x reference)
//
#include <hip/hip_runtime.h>

typedef __bf16 bf16_t;
typedef __bf16 bf16x8 __attribute__((ext_vector_type(8)));
typedef __bf16 bf16x4 __attribute__((ext_vector_type(4)));
typedef float f32x4 __attribute__((ext_vector_type(4)));

#define NNODES 24576

// ws layout (bytes):
//   0        W1b   (512*512 bf16)  = 524288
//   1048576  W4t   (512*1536 bf16) = 1572864
//   2621440  Wct   (512*512 bf16)  = 524288
//   3145728  bc    (512 f32)       = 2048
//   3147776  W2t   (512*512 bf16)  = 524288
//   3674112  A3    (24576*1536 bf16) = 75497472  [Wctp (4MB f32) overlaps A3
//            head: consumed by wct_reduce BEFORE gemm16x writes A3]
// d_out chunk0 (48MB f32 xbo, dead until final GEMM):
//   25165824 c3    (3*24576 f32)   = 294912
//   25460736 sbuf  (24576 f32)     = 98304

__device__ __forceinline__ void g2l16(const void* g, void* l) {
    __builtin_amdgcn_global_load_lds((__attribute__((address_space(1))) void*)(g),
                                     (__attribute__((address_space(3))) void*)(l),
                                     16, 0, 0);
}

#define SB()  __builtin_amdgcn_sched_barrier(0)
#define BAR() __builtin_amdgcn_s_barrier()

// ============ G-GEMM: A = f32 x consumed directly (fused cast) ============
// (unchanged R16 structure: BK=64, swizzled LDS, 1 block/CU)
__global__ __launch_bounds__(1024)
void gemm16x_kernel(const float* __restrict__ X, const bf16_t* __restrict__ Bt,
                    const float* __restrict__ bias, bf16_t* __restrict__ A3,
                    const float* __restrict__ W3, const float* __restrict__ c3v,
                    float* __restrict__ sbuf)
{
    __shared__ __align__(16) char smem[114688];
    char* baseA = smem;            // 2 x 24576 (192 rows x 128B per buf)
    char* baseB = smem + 49152;    // 2 x 32768 (256 rows x 128B per buf)

    const int tid  = threadIdx.x;
    const int lane = tid & 63;
    const int wave = tid >> 6;       // 0..15
    const int wr   = wave >> 2;
    const int wc   = wave & 3;
    const int l15  = lane & 15;
    const int lh   = lane >> 4;

    const int bm = blockIdx.x;
    const int bn = blockIdx.y;

    const size_t strbB = 1024;       // Wct row = 512 bf16

    const int q0 = tid * 16;
    const size_t roB = (size_t)(q0 >> 7) * strbB + ((q0 ^ (((q0 >> 7) & 7) << 4)) & 127);
    const char* gB = (const char*)Bt + (size_t)bn * 256 * strbB + roB;

    auto stageB = [&](int t, int buf) {
        const size_t kb = (size_t)t * 128;
        g2l16(gB + kb,                baseB + buf * 32768 + q0);
        g2l16(gB + kb + 128 * strbB,  baseB + buf * 32768 + 16384 + q0);
    };

    const int arow0 = tid >> 4;              // 0..63
    const int e4    = (tid & 15) * 4;        // f32 col 0..60
    const float* gx = X + (size_t)(bm * 192 + arow0) * 512 + e4;
    const int woff0 = ((arow0 * 128) + e4 * 2) ^ ((arow0 & 7) << 4);

    float4 fA[3];
    auto loadA = [&](int t) {
#pragma unroll
        for (int r = 0; r < 3; ++r)
            fA[r] = *(const float4*)(gx + (size_t)r * 64 * 512 + t * 64);
    };
    auto writeA = [&](int buf) {
        char* d = baseA + buf * 24576;
#pragma unroll
        for (int r = 0; r < 3; ++r) {
            bf16x4 o;
            o[0] = (bf16_t)fA[r].x; o[1] = (bf16_t)fA[r].y;
            o[2] = (bf16_t)fA[r].z; o[3] = (bf16_t)fA[r].w;
            *(bf16x4*)(d + r * 8192 + woff0) = o;
        }
    };

    const int swzr = (l15 & 7) << 4;
    const int xk0  = (lh * 16) ^ swzr;
    const int xk1  = (64 + lh * 16) ^ swzr;
    const int aOff = (wr * 48 + l15) * 128;
    const int bOff = (wc * 64 + l15) * 128;

    f32x4 acc[3][4] = {};

    loadA(0); stageB(0, 0);
    asm volatile("s_waitcnt vmcnt(2)" ::: "memory");
    writeA(0);

    for (int t = 0; t < 8; ++t) {
        const int buf = t & 1;

        asm volatile("s_waitcnt vmcnt(0) lgkmcnt(0)" ::: "memory");
        BAR();
        SB();

        if (t < 7) { loadA(t + 1); stageB(t + 1, buf ^ 1); }
        SB();

        bf16x8 af[3][2], bf[4][2];
        {
            const char* _pa = baseA + buf * 24576 + aOff;
#pragma unroll
            for (int m = 0; m < 3; ++m) {
                af[m][0] = *(const bf16x8*)(_pa + m * 2048 + xk0);
                af[m][1] = *(const bf16x8*)(_pa + m * 2048 + xk1);
            }
            const char* _pb = baseB + buf * 32768 + bOff;
#pragma unroll
            for (int n = 0; n < 4; ++n) {
                bf[n][0] = *(const bf16x8*)(_pb + n * 2048 + xk0);
                bf[n][1] = *(const bf16x8*)(_pb + n * 2048 + xk1);
            }
        }

        __builtin_amdgcn_s_setprio(1);
#pragma unroll
        for (int m = 0; m < 3; ++m)
#pragma unroll
        for (int n = 0; n < 4; ++n)
#pragma unroll
        for (int kk = 0; kk < 2; ++kk)
            acc[m][n] = __builtin_amdgcn_mfma_f32_16x16x32_bf16(
                af[m][kk], bf[n][kk], acc[m][n], 0, 0, 0);
        __builtin_amdgcn_s_setprio(0);

        if (t < 7) {
            asm volatile("s_waitcnt vmcnt(2)" ::: "memory");
            SB();
            writeA(buf ^ 1);
        }
        SB();
    }

    // ---- epilogue ----
    BAR();
    bf16_t* sg = (bf16_t*)smem;
    const int gr0 = bm * 192 + wr * 48 + lh * 4;
    const int gc0 = bn * 256 + wc * 64 + l15;
    const int lr0 = wr * 48 + lh * 4;
    const int lc0 = wc * 64 + l15;
    float w3v[4], bv[4];
#pragma unroll
    for (int n = 0; n < 4; ++n) {
        w3v[n] = W3[gc0 + n * 16];
        bv[n]  = bias[gc0 + n * 16];
    }
#pragma unroll
    for (int m = 0; m < 3; ++m)
#pragma unroll
    for (int j = 0; j < 4; ++j) {
        const int r = gr0 + m * 16 + j;
        float g[4], p = 0.f;
#pragma unroll
        for (int n = 0; n < 4; ++n) {
            g[n] = acc[m][n][j] + bv[n];
            p += g[n] * w3v[n];
        }
        p += __shfl_xor(p, 1); p += __shfl_xor(p, 2);
        p += __shfl_xor(p, 4); p += __shfl_xor(p, 8);
        if (l15 == 0) atomicAdd(&sbuf[r], p);
        bf16_t* srow = sg + (lr0 + m * 16 + j) * 264 + lc0;
#pragma unroll
        for (int n = 0; n < 4; ++n)
            srow[n * 16] = (bf16_t)(g[n] * g[n]);
    }
    BAR();
    const int rl = tid >> 5;
    const int cb = (tid & 31) * 8;
#pragma unroll
    for (int pass = 0; pass < 6; ++pass) {
        const int row = pass * 32 + rl;
        const bf16x8 v = *(const bf16x8*)((const char*)sg + row * 528 + cb * 2);
        float f[8];
#pragma unroll
        for (int j = 0; j < 8; ++j) f[j] = (float)v[j];
        const int grow = bm * 192 + row;
#pragma unroll
        for (int l = 0; l < 3; ++l) {
            const float c = c3v[grow + l * NNODES];
            bf16x8 o;
#pragma unroll
            for (int j = 0; j < 8; ++j) o[j] = (bf16_t)(c * f[j]);
            *(bf16x8*)(A3 + (size_t)grow * 1536 + l * 512 + bn * 256 + cb) = o;
        }
    }
}

// ============ final GEMM: BK=32, 56KB LDS -> 2 blocks/CU ============
// Tile 192x256, 16 waves (4x4), per-wave 48x64; 12 MFMA + 7 ds_read_b128/tile.
// Row = 64B at BK=32 -> wave frag reads cover contiguous 1024B: conflict-free
// WITHOUT swizzle; staging is plain linear g2l16. Two independent blocks per
// CU overlap each other's barrier/drain bubbles.
__global__ __launch_bounds__(1024, 8)
void gemm16_kernel(const bf16_t* __restrict__ A, const bf16_t* __restrict__ Bt,
                   const float* __restrict__ bias, void* __restrict__ Cout,
                   int N, int K, int mode)
{
    __shared__ __align__(16) bf16_t lA[2][6144];   // 192 rows x 64B per buf (12KB)
    __shared__ __align__(16) bf16_t lB[2][8192];   // 256 rows x 64B per buf (16KB)

    const int tid  = threadIdx.x;
    const int lane = tid & 63;
    const int wave = tid >> 6;
    const int wr   = wave >> 2;      // 0..3
    const int wc   = wave & 3;       // 0..3
    const int l15  = lane & 15;
    const int lh   = lane >> 4;

    const int bm = blockIdx.x;
    const int bn = blockIdx.y;

    const size_t strb = (size_t)K * 2;

    // staging: q0 = linear byte; row = q0>>6 (64B rows), linear (no swizzle)
    const int q0 = tid * 16;
    const size_t ro = (size_t)(q0 >> 6) * strb + (q0 & 63);
    const char* gA = (const char*)A  + (size_t)bm * 192 * strb + ro;   // tid<768
    const char* gB = (const char*)Bt + (size_t)bn * 256 * strb + ro;   // all
    char* baseA = (char*)&lA[0][0];
    char* baseB = (char*)&lB[0][0];

    auto stage = [&](int t, int buf) {
        const size_t kb = (size_t)t * 64;
        if (tid < 768) g2l16(gA + kb, baseA + buf * 12288 + q0);
        g2l16(gB + kb, baseB + buf * 16384 + q0);
    };

    const int xo   = lh * 16;                       // byte within 64B row
    const int aOff = (wr * 48 + l15) * 64 + xo;
    const int bOff = (wc * 64 + l15) * 64 + xo;

    f32x4 acc[3][4] = {};

    const int T = K / 32;
    stage(0, 0);

    for (int t = 0; t < T; ++t) {
        const int buf = t & 1;

        asm volatile("s_waitcnt vmcnt(0)" ::: "memory");  // tile-t loads: 1 tile old
        BAR();
        SB();

        if (t + 1 < T) stage(t + 1, buf ^ 1);
        SB();

        bf16x8 af[3], bf[4];
        {
            const char* _pa = baseA + buf * 12288 + aOff;
#pragma unroll
            for (int m = 0; m < 3; ++m)
                af[m] = *(const bf16x8*)(_pa + m * 1024);   // +16 rows
            const char* _pb = baseB + buf * 16384 + bOff;
#pragma unroll
            for (int n = 0; n < 4; ++n)
                bf[n] = *(const bf16x8*)(_pb + n * 1024);
        }

        __builtin_amdgcn_s_setprio(1);
#pragma unroll
        for (int m = 0; m < 3; ++m)
#pragma unroll
        for (int n = 0; n < 4; ++n)
            acc[m][n] = __builtin_amdgcn_mfma_f32_16x16x32_bf16(
                af[m], bf[n], acc[m][n], 0, 0, 0);
        __builtin_amdgcn_s_setprio(0);
    }

    const int gr0 = bm * 192 + wr * 48 + lh * 4;
    const int gc0 = bn * 256 + wc * 64 + l15;
    if (mode == 0) {
        bf16_t* C = (bf16_t*)Cout;
#pragma unroll
        for (int m = 0; m < 3; ++m)
#pragma unroll
        for (int n = 0; n < 4; ++n) {
            const int c = gc0 + n * 16;
            const float bv = bias ? bias[c] : 0.f;
#pragma unroll
            for (int j = 0; j < 4; ++j)
                C[(size_t)(gr0 + m * 16 + j) * N + c] = (bf16_t)(acc[m][n][j] + bv);
        }
    } else {
        float* C = (float*)Cout;
#pragma unroll
        for (int m = 0; m < 3; ++m)
#pragma unroll
        for (int n = 0; n < 4; ++n) {
            const int c = gc0 + n * 16;
            const float bv = bias[c];
#pragma unroll
            for (int j = 0; j < 4; ++j) {
                float v = acc[m][n][j] + bv;
                C[(size_t)(gr0 + m * 16 + j) * N + c] = v / (1.f + __expf(-v));
            }
        }
    }
}

// ============ 8-wave GEMM (split-K) — Wct partials only ============
__global__ __launch_bounds__(512)
void gemm8_kernel(const bf16_t* __restrict__ A, const bf16_t* __restrict__ Bt,
                  void* __restrict__ Cout, int N, int K, int LD)
{
    __shared__ __align__(16) bf16_t lA[2][16384];
    __shared__ __align__(16) bf16_t lB[2][16384];

    const int tid  = threadIdx.x;
    const int lane = tid & 63;
    const int wave = tid >> 6;
    const int wr   = wave >> 2;
    const int wc   = wave & 3;
    const int l15  = lane & 15;
    const int lh   = lane >> 4;

    const int bm = blockIdx.x;
    const int bn = blockIdx.y;
    const int bz = blockIdx.z;

    const size_t strb = (size_t)LD * 2;
    const size_t zoff = (size_t)bz * K * 2;

    const int q0 = tid * 16;
    const size_t rowOff = (size_t)(q0 >> 7) * strb + ((q0 ^ (((q0 >> 7) & 7) << 4)) & 127);
    const char* gA = (const char*)A  + (size_t)bm * 256 * strb + zoff + rowOff;
    const char* gB = (const char*)Bt + (size_t)bn * 256 * strb + zoff + rowOff;
    char* baseA = (char*)&lA[0][0];
    char* baseB = (char*)&lB[0][0];

    auto stageA = [&](int t, int buf, int r) {
        g2l16(gA + (size_t)t * 128 + (size_t)(r * 64) * strb,
              baseA + buf * 32768 + r * 8192 + q0);
    };
    auto stageB = [&](int t, int buf, int r) {
        g2l16(gB + (size_t)t * 128 + (size_t)(r * 64) * strb,
              baseB + buf * 32768 + r * 8192 + q0);
    };

    const int swzr = (l15 & 7) << 4;
    const int xk0  = (lh * 16) ^ swzr;
    const int xk1  = (64 + lh * 16) ^ swzr;
    const int aOff = wr * 16384 + l15 * 128;
    const int bOff = wc * 8192 + l15 * 128;

    f32x4 acc[2][2][4][2] = {};

    const int T = K / 64;

#pragma unroll
    for (int r = 0; r < 4; ++r) { stageA(0, 0, r); stageB(0, 0, r); }

    for (int t = 0; t < T; ++t) {
        const int buf = t & 1, nbuf = buf ^ 1;

        asm volatile("s_waitcnt vmcnt(0)" ::: "memory");
        BAR();
        SB();

        if (t + 1 < T) {
#pragma unroll
            for (int r = 0; r < 4; ++r) { stageA(t + 1, nbuf, r); stageB(t + 1, nbuf, r); }
        }
        SB();

        bf16x8 af[8][2], bf[4][2];
        {
            const char* _pa = baseA + buf * 32768 + aOff;
#pragma unroll
            for (int i = 0; i < 8; ++i) {
                af[i][0] = *(const bf16x8*)(_pa + i * 2048 + xk0);
                af[i][1] = *(const bf16x8*)(_pa + i * 2048 + xk1);
            }
            const char* _pb = baseB + buf * 32768 + bOff;
#pragma unroll
            for (int j = 0; j < 4; ++j) {
                bf[j][0] = *(const bf16x8*)(_pb + j * 2048 + xk0);
                bf[j][1] = *(const bf16x8*)(_pb + j * 2048 + xk1);
            }
        }

        __builtin_amdgcn_s_setprio(1);
#pragma unroll
        for (int mh = 0; mh < 2; ++mh)
#pragma unroll
        for (int nh = 0; nh < 2; ++nh)
#pragma unroll
        for (int m = 0; m < 4; ++m)
#pragma unroll
        for (int n = 0; n < 2; ++n)
#pragma unroll
        for (int kk = 0; kk < 2; ++kk)
            acc[mh][nh][m][n] = __builtin_amdgcn_mfma_f32_16x16x32_bf16(
                af[mh * 4 + m][kk], bf[nh * 2 + n][kk], acc[mh][nh][m][n], 0, 0, 0);
        __builtin_amdgcn_s_setprio(0);
    }

    float* C = (float*)Cout + (size_t)bz * 512 * 512;
    const int gr0 = bm * 256 + wr * 128 + lh * 4;
    const int gc0 = bn * 256 + wc * 64 + l15;
#pragma unroll
    for (int mh = 0; mh < 2; ++mh)
#pragma unroll
    for (int nh = 0; nh < 2; ++nh)
#pragma unroll
    for (int m = 0; m < 4; ++m)
#pragma unroll
    for (int n = 0; n < 2; ++n) {
        const int c = gc0 + nh * 32 + n * 16;
#pragma unroll
        for (int j = 0; j < 4; ++j)
            C[(size_t)(gr0 + (mh * 4 + m) * 16 + j) * N + c] = acc[mh][nh][m][n][j];
    }
}

__global__ void wct_reduce_kernel(const float* __restrict__ p, bf16_t* __restrict__ out) {
    const int i = blockIdx.x * 256 + threadIdx.x;   // < 262144
    out[i] = (bf16_t)(p[i] + p[i + 262144] + p[i + 524288] + p[i + 786432]);
}

// W1 f32 -> bf16 cast (coalesced)
__global__ void prepw1_kernel(const float* __restrict__ W1, bf16_t* __restrict__ W1b) {
    const int i = blockIdx.x * 256 + threadIdx.x;
    const float4* p = (const float4*)W1 + (size_t)i * 2;
    float4 a = p[0], c = p[1];
    bf16x8 v;
    v[0] = (bf16_t)a.x; v[1] = (bf16_t)a.y; v[2] = (bf16_t)a.z; v[3] = (bf16_t)a.w;
    v[4] = (bf16_t)c.x; v[5] = (bf16_t)c.y; v[6] = (bf16_t)c.z; v[7] = (bf16_t)c.w;
    *(bf16x8*)(W1b + (size_t)i * 8) = v;
}

// LDS-tiled transpose+cast: in is R rows x C cols; out[c*R + r] = bf16(in[r*C + c]).
// Launch: grid (C/64, R/64).
__global__ __launch_bounds__(256)
void tr_kernel(const float* __restrict__ in, bf16_t* __restrict__ out, int R, int C) {
    __shared__ float tile[64][65];
    const int c0 = blockIdx.x * 64, r0 = blockIdx.y * 64;
    const int tx = threadIdx.x & 63, ty = threadIdx.x >> 6;   // ty 0..3
#pragma unroll
    for (int p = 0; p < 16; ++p) {
        const int r = p * 4 + ty;
        tile[r][tx] = in[(size_t)(r0 + r) * C + c0 + tx];
    }
    __syncthreads();
#pragma unroll
    for (int p = 0; p < 16; ++p) {
        const int c = p * 4 + ty;
        out[(size_t)(c0 + c) * R + r0 + tx] = (bf16_t)tile[tx][c];
    }
}

// bc[t] = sum_i b1[i] * W2[i][t]
__global__ void vecmat_kernel(const float* __restrict__ v, const float* __restrict__ W,
                              float* __restrict__ out) {
    const int t = blockIdx.x * blockDim.x + threadIdx.x;
    if (t >= 512) return;
    float s = 0.f;
    for (int i = 0; i < 512; ++i) s += v[i] * W[i * 512 + t];
    out[t] = s;
}

// c3[l][n] = sum_{m in seg l} chi[n,m]^2 ; also zeroes sbuf (replay-safe)
__global__ void c3_kernel(const float* __restrict__ chi, float* __restrict__ c3,
                          float* __restrict__ sbuf) {
    const int n = blockIdx.x * 256 + threadIdx.x;
    if (n >= NNODES) return;
    const float* ch = chi + (size_t)n * 15;
    float a = 0.f, b = 0.f, c = 0.f;
#pragma unroll
    for (int m = 0; m < 3; ++m)  a += ch[m] * ch[m];
#pragma unroll
    for (int m = 3; m < 8; ++m)  b += ch[m] * ch[m];
#pragma unroll
    for (int m = 8; m < 15; ++m) c += ch[m] * ch[m];
    c3[n] = a; c3[n + NNODES] = b; c3[n + 2 * NNODES] = c;
    sbuf[n] = 0.f;
}

// chbo[n,m] = chi[n,m] * s[n]
__global__ void chbo_kernel(const float* __restrict__ chi, const float* __restrict__ s,
                            float* __restrict__ chbo) {
    const int idx = blockIdx.x * 256 + threadIdx.x;
    if (idx >= NNODES * 15) return;
    chbo[idx] = chi[idx] * s[idx / 15];
}

extern "C" void kernel_launch(void* const* d_in, const int* in_sizes, int n_in,
                              void* d_out, int out_size, void* d_ws, size_t ws_size,
                              hipStream_t stream)
{
    const float* x   = (const float*)d_in[0];
    const float* chi = (const float*)d_in[1];
    // d_in[2] = z_one_hot : unused
    const float* W1  = (const float*)d_in[3];
    const float* b1  = (const float*)d_in[4];
    const float* W2  = (const float*)d_in[5];
    const float* W3  = (const float*)d_in[6];
    const float* W4  = (const float*)d_in[7];
    const float* b4  = (const float*)d_in[8];

    char* ws = (char*)d_ws;
    bf16_t* W1b  = (bf16_t*)(ws + 0);
    bf16_t* W4t  = (bf16_t*)(ws + 1048576);
    bf16_t* Wct  = (bf16_t*)(ws + 2621440);
    float*  bc   = (float*) (ws + 3145728);
    bf16_t* W2t  = (bf16_t*)(ws + 3147776);
    bf16_t* A3   = (bf16_t*)(ws + 3674112);
    float*  Wctp = (float*) (ws + 3674112);   // overlaps A3 head; dead before A3 written

    float*  xbo  = (float*)d_out;                          // 24576*512 f32
    float*  chbo = (float*)d_out + (size_t)NNODES * 512;   // 24576*15 f32
    char*   c0s  = (char*)d_out;
    float*  c3   = (float*) (c0s + 25165824);
    float*  sbuf = (float*) (c0s + 25460736);

    // prep (coalesced)
    prepw1_kernel<<<128, 256, 0, stream>>>(W1, W1b);
    tr_kernel<<<dim3(8, 8),  256, 0, stream>>>(W2, W2t, 512, 512);
    tr_kernel<<<dim3(8, 24), 256, 0, stream>>>(W4, W4t, 1536, 512);
    vecmat_kernel<<<2, 256, 0, stream>>>(b1, W2, bc);      // bc = b1 @ W2
    c3_kernel<<<96, 256, 0, stream>>>(chi, c3, sbuf);

    // Wct = (W1@W2)^T via split-K partials + reduce
    gemm8_kernel<<<dim3(2, 2, 4), 512, 0, stream>>>(W2t, W1b, Wctp, 512, 128, 512);
    wct_reduce_kernel<<<1024, 256, 0, stream>>>(Wctp, Wct);

    // G-GEMM (consumes f32 x directly): A3 = c_l * g^2 (coalesced) ; sbuf += g.W3
    gemm16x_kernel<<<dim3(128, 2), 1024, 0, stream>>>(x, Wct, bc, A3, W3, c3, sbuf);

    // chi_bo = chi * s
    chbo_kernel<<<1440, 256, 0, stream>>>(chi, sbuf, chbo);

    // x_bo = silu(A3 @ W4 + b4)  — BK=32, 2 blocks/CU
    gemm16_kernel<<<dim3(128, 2), 1024, 0, stream>>>(A3, W4t, b4, xbo, 512, 1536, 1);
}

// Round 19
// 139.514 us; speedup vs baseline: 3.3211x; 3.3211x over previous
//
#include <hip/hip_runtime.h>

typedef __bf16 bf16_t;
typedef __bf16 bf16x8 __attribute__((ext_vector_type(8)));
typedef __bf16 bf16x4 __attribute__((ext_vector_type(4)));
typedef float f32x4 __attribute__((ext_vector_type(4)));

#define BK 64
#define NNODES 24576

// ws layout (bytes):
//   0        W1b   (512*512 bf16)  = 524288
//   1048576  W4t   (512*1536 bf16) = 1572864
//   2621440  Wct   (512*512 bf16)  = 524288
//   3145728  bc    (512 f32)       = 2048
//   3147776  W2t   (512*512 bf16)  = 524288
//   3674112  A3    (24576*1536 bf16) = 75497472  [Wctp (4MB f32) overlaps A3
//            head: consumed by wct_reduce BEFORE gemm16x writes A3]
// d_out chunk0 (48MB f32 xbo, dead until final GEMM):
//   25165824 c3    (3*24576 f32)   = 294912
//   25460736 sbuf  (24576 f32)     = 98304

__device__ __forceinline__ void g2l16(const void* g, void* l) {
    __builtin_amdgcn_global_load_lds((__attribute__((address_space(1))) void*)(g),
                                     (__attribute__((address_space(3))) void*)(l),
                                     16, 0, 0);
}

#define SB()  __builtin_amdgcn_sched_barrier(0)
#define BAR() __builtin_amdgcn_s_barrier()

// ============ G-GEMM: A = f32 x consumed directly (fused cast) ============
__global__ __launch_bounds__(1024)
void gemm16x_kernel(const float* __restrict__ X, const bf16_t* __restrict__ Bt,
                    const float* __restrict__ bias, bf16_t* __restrict__ A3,
                    const float* __restrict__ W3, const float* __restrict__ c3v,
                    float* __restrict__ sbuf)
{
    __shared__ __align__(16) char smem[114688];
    char* baseA = smem;            // 2 x 24576 (192 rows x 128B per buf)
    char* baseB = smem + 49152;    // 2 x 32768 (256 rows x 128B per buf)

    const int tid  = threadIdx.x;
    const int lane = tid & 63;
    const int wave = tid >> 6;       // 0..15
    const int wr   = wave >> 2;
    const int wc   = wave & 3;
    const int l15  = lane & 15;
    const int lh   = lane >> 4;

    const int bm = blockIdx.x;
    const int bn = blockIdx.y;

    const size_t strbB = 1024;       // Wct row = 512 bf16

    const int q0 = tid * 16;
    const size_t roB = (size_t)(q0 >> 7) * strbB + ((q0 ^ (((q0 >> 7) & 7) << 4)) & 127);
    const char* gB = (const char*)Bt + (size_t)bn * 256 * strbB + roB;

    auto stageB = [&](int t, int buf) {
        const size_t kb = (size_t)t * 128;
        g2l16(gB + kb,                baseB + buf * 32768 + q0);
        g2l16(gB + kb + 128 * strbB,  baseB + buf * 32768 + 16384 + q0);
    };

    const int arow0 = tid >> 4;              // 0..63
    const int e4    = (tid & 15) * 4;        // f32 col 0..60
    const float* gx = X + (size_t)(bm * 192 + arow0) * 512 + e4;
    const int woff0 = ((arow0 * 128) + e4 * 2) ^ ((arow0 & 7) << 4);

    float4 fA[3];
    auto loadA = [&](int t) {
#pragma unroll
        for (int r = 0; r < 3; ++r)
            fA[r] = *(const float4*)(gx + (size_t)r * 64 * 512 + t * 64);
    };
    auto writeA = [&](int buf) {
        char* d = baseA + buf * 24576;
#pragma unroll
        for (int r = 0; r < 3; ++r) {
            bf16x4 o;
            o[0] = (bf16_t)fA[r].x; o[1] = (bf16_t)fA[r].y;
            o[2] = (bf16_t)fA[r].z; o[3] = (bf16_t)fA[r].w;
            *(bf16x4*)(d + r * 8192 + woff0) = o;
        }
    };

    const int swzr = (l15 & 7) << 4;
    const int xk0  = (lh * 16) ^ swzr;
    const int xk1  = (64 + lh * 16) ^ swzr;
    const int aOff = (wr * 48 + l15) * 128;
    const int bOff = (wc * 64 + l15) * 128;

    f32x4 acc[3][4] = {};

    loadA(0); stageB(0, 0);
    asm volatile("s_waitcnt vmcnt(2)" ::: "memory");
    writeA(0);

    for (int t = 0; t < 8; ++t) {
        const int buf = t & 1;

        asm volatile("s_waitcnt vmcnt(0) lgkmcnt(0)" ::: "memory");
        BAR();
        SB();

        if (t < 7) { loadA(t + 1); stageB(t + 1, buf ^ 1); }
        SB();

        bf16x8 af[3][2], bf[4][2];
        {
            const char* _pa = baseA + buf * 24576 + aOff;
#pragma unroll
            for (int m = 0; m < 3; ++m) {
                af[m][0] = *(const bf16x8*)(_pa + m * 2048 + xk0);
                af[m][1] = *(const bf16x8*)(_pa + m * 2048 + xk1);
            }
            const char* _pb = baseB + buf * 32768 + bOff;
#pragma unroll
            for (int n = 0; n < 4; ++n) {
                bf[n][0] = *(const bf16x8*)(_pb + n * 2048 + xk0);
                bf[n][1] = *(const bf16x8*)(_pb + n * 2048 + xk1);
            }
        }

        __builtin_amdgcn_s_setprio(1);
#pragma unroll
        for (int m = 0; m < 3; ++m)
#pragma unroll
        for (int n = 0; n < 4; ++n)
#pragma unroll
        for (int kk = 0; kk < 2; ++kk)
            acc[m][n] = __builtin_amdgcn_mfma_f32_16x16x32_bf16(
                af[m][kk], bf[n][kk], acc[m][n], 0, 0, 0);
        __builtin_amdgcn_s_setprio(0);

        if (t < 7) {
            asm volatile("s_waitcnt vmcnt(2)" ::: "memory");
            SB();
            writeA(buf ^ 1);
        }
        SB();
    }

    // ---- epilogue ----
    BAR();
    bf16_t* sg = (bf16_t*)smem;
    const int gr0 = bm * 192 + wr * 48 + lh * 4;
    const int gc0 = bn * 256 + wc * 64 + l15;
    const int lr0 = wr * 48 + lh * 4;
    const int lc0 = wc * 64 + l15;
    float w3v[4], bv[4];
#pragma unroll
    for (int n = 0; n < 4; ++n) {
        w3v[n] = W3[gc0 + n * 16];
        bv[n]  = bias[gc0 + n * 16];
    }
#pragma unroll
    for (int m = 0; m < 3; ++m)
#pragma unroll
    for (int j = 0; j < 4; ++j) {
        const int r = gr0 + m * 16 + j;
        float g[4], p = 0.f;
#pragma unroll
        for (int n = 0; n < 4; ++n) {
            g[n] = acc[m][n][j] + bv[n];
            p += g[n] * w3v[n];
        }
        p += __shfl_xor(p, 1); p += __shfl_xor(p, 2);
        p += __shfl_xor(p, 4); p += __shfl_xor(p, 8);
        if (l15 == 0) atomicAdd(&sbuf[r], p);
        bf16_t* srow = sg + (lr0 + m * 16 + j) * 264 + lc0;
#pragma unroll
        for (int n = 0; n < 4; ++n)
            srow[n * 16] = (bf16_t)(g[n] * g[n]);
    }
    BAR();
    const int rl = tid >> 5;
    const int cb = (tid & 31) * 8;
#pragma unroll
    for (int pass = 0; pass < 6; ++pass) {
        const int row = pass * 32 + rl;
        const bf16x8 v = *(const bf16x8*)((const char*)sg + row * 528 + cb * 2);
        float f[8];
#pragma unroll
        for (int j = 0; j < 8; ++j) f[j] = (float)v[j];
        const int grow = bm * 192 + row;
#pragma unroll
        for (int l = 0; l < 3; ++l) {
            const float c = c3v[grow + l * NNODES];
            bf16x8 o;
#pragma unroll
            for (int j = 0; j < 8; ++j) o[j] = (bf16_t)(c * f[j]);
            *(bf16x8*)(A3 + (size_t)grow * 1536 + l * 512 + bn * 256 + cb) = o;
        }
    }
}

// ============ 16-wave GEMM (bf16 A, BK=64) — final GEMM (R16-proven) ============
__global__ __launch_bounds__(1024)
void gemm16_kernel(const bf16_t* __restrict__ A, const bf16_t* __restrict__ Bt,
                   const float* __restrict__ bias, void* __restrict__ Cout,
                   int N, int K, int mode)
{
    __shared__ __align__(16) bf16_t lA[2][12288];
    __shared__ __align__(16) bf16_t lB[2][16384];

    const int tid  = threadIdx.x;
    const int lane = tid & 63;
    const int wave = tid >> 6;
    const int wr   = wave >> 2;
    const int wc   = wave & 3;
    const int l15  = lane & 15;
    const int lh   = lane >> 4;

    const int bm = blockIdx.x;
    const int bn = blockIdx.y;

    const size_t strb = (size_t)K * 2;

    const int q0 = tid * 16;
    const size_t ro = (size_t)(q0 >> 7) * strb + ((q0 ^ (((q0 >> 7) & 7) << 4)) & 127);
    const char* gA = (const char*)A  + (size_t)bm * 192 * strb + ro;
    const char* gB = (const char*)Bt + (size_t)bn * 256 * strb + ro;
    char* baseA = (char*)&lA[0][0];
    char* baseB = (char*)&lB[0][0];

    auto stage = [&](int t, int buf) {
        const size_t kb = (size_t)t * 128;
        g2l16(gA + kb, baseA + buf * 24576 + q0);
        if (tid < 512)
            g2l16(gA + kb + 128 * strb, baseA + buf * 24576 + 16384 + q0);
        g2l16(gB + kb, baseB + buf * 32768 + q0);
        g2l16(gB + kb + 128 * strb, baseB + buf * 32768 + 16384 + q0);
    };

    const int swzr = (l15 & 7) << 4;
    const int xk0  = (lh * 16) ^ swzr;
    const int xk1  = (64 + lh * 16) ^ swzr;
    const int aOff = (wr * 48 + l15) * 128;
    const int bOff = (wc * 64 + l15) * 128;

    f32x4 acc[3][4] = {};

    const int T = K / BK;
    stage(0, 0);

    for (int t = 0; t < T; ++t) {
        const int buf = t & 1;

        asm volatile("s_waitcnt vmcnt(0)" ::: "memory");
        BAR();
        SB();

        if (t + 1 < T) stage(t + 1, buf ^ 1);
        SB();

        bf16x8 af[3][2], bf[4][2];
        {
            const char* _pa = baseA + buf * 24576 + aOff;
#pragma unroll
            for (int m = 0; m < 3; ++m) {
                af[m][0] = *(const bf16x8*)(_pa + m * 2048 + xk0);
                af[m][1] = *(const bf16x8*)(_pa + m * 2048 + xk1);
            }
            const char* _pb = baseB + buf * 32768 + bOff;
#pragma unroll
            for (int n = 0; n < 4; ++n) {
                bf[n][0] = *(const bf16x8*)(_pb + n * 2048 + xk0);
                bf[n][1] = *(const bf16x8*)(_pb + n * 2048 + xk1);
            }
        }

        __builtin_amdgcn_s_setprio(1);
#pragma unroll
        for (int m = 0; m < 3; ++m)
#pragma unroll
        for (int n = 0; n < 4; ++n)
#pragma unroll
        for (int kk = 0; kk < 2; ++kk)
            acc[m][n] = __builtin_amdgcn_mfma_f32_16x16x32_bf16(
                af[m][kk], bf[n][kk], acc[m][n], 0, 0, 0);
        __builtin_amdgcn_s_setprio(0);
    }

    const int gr0 = bm * 192 + wr * 48 + lh * 4;
    const int gc0 = bn * 256 + wc * 64 + l15;
    if (mode == 0) {
        bf16_t* C = (bf16_t*)Cout;
#pragma unroll
        for (int m = 0; m < 3; ++m)
#pragma unroll
        for (int n = 0; n < 4; ++n) {
            const int c = gc0 + n * 16;
            const float bv = bias ? bias[c] : 0.f;
#pragma unroll
            for (int j = 0; j < 4; ++j)
                C[(size_t)(gr0 + m * 16 + j) * N + c] = (bf16_t)(acc[m][n][j] + bv);
        }
    } else {
        float* C = (float*)Cout;
#pragma unroll
        for (int m = 0; m < 3; ++m)
#pragma unroll
        for (int n = 0; n < 4; ++n) {
            const int c = gc0 + n * 16;
            const float bv = bias[c];
#pragma unroll
            for (int j = 0; j < 4; ++j) {
                float v = acc[m][n][j] + bv;
                C[(size_t)(gr0 + m * 16 + j) * N + c] = v / (1.f + __expf(-v));
            }
        }
    }
}

// ============ 8-wave GEMM (split-K) — Wct partials only ============
__global__ __launch_bounds__(512)
void gemm8_kernel(const bf16_t* __restrict__ A, const bf16_t* __restrict__ Bt,
                  void* __restrict__ Cout, int N, int K, int LD)
{
    __shared__ __align__(16) bf16_t lA[2][16384];
    __shared__ __align__(16) bf16_t lB[2][16384];

    const int tid  = threadIdx.x;
    const int lane = tid & 63;
    const int wave = tid >> 6;
    const int wr   = wave >> 2;
    const int wc   = wave & 3;
    const int l15  = lane & 15;
    const int lh   = lane >> 4;

    const int bm = blockIdx.x;
    const int bn = blockIdx.y;
    const int bz = blockIdx.z;

    const size_t strb = (size_t)LD * 2;
    const size_t zoff = (size_t)bz * K * 2;

    const int q0 = tid * 16;
    const size_t rowOff = (size_t)(q0 >> 7) * strb + ((q0 ^ (((q0 >> 7) & 7) << 4)) & 127);
    const char* gA = (const char*)A  + (size_t)bm * 256 * strb + zoff + rowOff;
    const char* gB = (const char*)Bt + (size_t)bn * 256 * strb + zoff + rowOff;
    char* baseA = (char*)&lA[0][0];
    char* baseB = (char*)&lB[0][0];

    auto stageA = [&](int t, int buf, int r) {
        g2l16(gA + (size_t)t * 128 + (size_t)(r * 64) * strb,
              baseA + buf * 32768 + r * 8192 + q0);
    };
    auto stageB = [&](int t, int buf, int r) {
        g2l16(gB + (size_t)t * 128 + (size_t)(r * 64) * strb,
              baseB + buf * 32768 + r * 8192 + q0);
    };

    const int swzr = (l15 & 7) << 4;
    const int xk0  = (lh * 16) ^ swzr;
    const int xk1  = (64 + lh * 16) ^ swzr;
    const int aOff = wr * 16384 + l15 * 128;
    const int bOff = wc * 8192 + l15 * 128;

    f32x4 acc[2][2][4][2] = {};

    const int T = K / BK;

#pragma unroll
    for (int r = 0; r < 4; ++r) { stageA(0, 0, r); stageB(0, 0, r); }

    for (int t = 0; t < T; ++t) {
        const int buf = t & 1, nbuf = buf ^ 1;

        asm volatile("s_waitcnt vmcnt(0)" ::: "memory");
        BAR();
        SB();

        if (t + 1 < T) {
#pragma unroll
            for (int r = 0; r < 4; ++r) { stageA(t + 1, nbuf, r); stageB(t + 1, nbuf, r); }
        }
        SB();

        bf16x8 af[8][2], bf[4][2];
        {
            const char* _pa = baseA + buf * 32768 + aOff;
#pragma unroll
            for (int i = 0; i < 8; ++i) {
                af[i][0] = *(const bf16x8*)(_pa + i * 2048 + xk0);
                af[i][1] = *(const bf16x8*)(_pa + i * 2048 + xk1);
            }
            const char* _pb = baseB + buf * 32768 + bOff;
#pragma unroll
            for (int j = 0; j < 4; ++j) {
                bf[j][0] = *(const bf16x8*)(_pb + j * 2048 + xk0);
                bf[j][1] = *(const bf16x8*)(_pb + j * 2048 + xk1);
            }
        }

        __builtin_amdgcn_s_setprio(1);
#pragma unroll
        for (int mh = 0; mh < 2; ++mh)
#pragma unroll
        for (int nh = 0; nh < 2; ++nh)
#pragma unroll
        for (int m = 0; m < 4; ++m)
#pragma unroll
        for (int n = 0; n < 2; ++n)
#pragma unroll
        for (int kk = 0; kk < 2; ++kk)
            acc[mh][nh][m][n] = __builtin_amdgcn_mfma_f32_16x16x32_bf16(
                af[mh * 4 + m][kk], bf[nh * 2 + n][kk], acc[mh][nh][m][n], 0, 0, 0);
        __builtin_amdgcn_s_setprio(0);
    }

    float* C = (float*)Cout + (size_t)bz * 512 * 512;
    const int gr0 = bm * 256 + wr * 128 + lh * 4;
    const int gc0 = bn * 256 + wc * 64 + l15;
#pragma unroll
    for (int mh = 0; mh < 2; ++mh)
#pragma unroll
    for (int nh = 0; nh < 2; ++nh)
#pragma unroll
    for (int m = 0; m < 4; ++m)
#pragma unroll
    for (int n = 0; n < 2; ++n) {
        const int c = gc0 + nh * 32 + n * 16;
#pragma unroll
        for (int j = 0; j < 4; ++j)
            C[(size_t)(gr0 + (mh * 4 + m) * 16 + j) * N + c] = acc[mh][nh][m][n][j];
    }
}

__global__ void wct_reduce_kernel(const float* __restrict__ p, bf16_t* __restrict__ out) {
    const int i = blockIdx.x * 256 + threadIdx.x;   // < 262144
    out[i] = (bf16_t)(p[i] + p[i + 262144] + p[i + 524288] + p[i + 786432]);
}

// W1 f32 -> bf16 cast (coalesced)
__global__ void prepw1_kernel(const float* __restrict__ W1, bf16_t* __restrict__ W1b) {
    const int i = blockIdx.x * 256 + threadIdx.x;
    const float4* p = (const float4*)W1 + (size_t)i * 2;
    float4 a = p[0], c = p[1];
    bf16x8 v;
    v[0] = (bf16_t)a.x; v[1] = (bf16_t)a.y; v[2] = (bf16_t)a.z; v[3] = (bf16_t)a.w;
    v[4] = (bf16_t)c.x; v[5] = (bf16_t)c.y; v[6] = (bf16_t)c.z; v[7] = (bf16_t)c.w;
    *(bf16x8*)(W1b + (size_t)i * 8) = v;
}

// LDS-tiled transpose+cast: in is R rows x C cols; out[c*R + r] = bf16(in[r*C + c]).
// Launch: grid (C/64, R/64).
__global__ __launch_bounds__(256)
void tr_kernel(const float* __restrict__ in, bf16_t* __restrict__ out, int R, int C) {
    __shared__ float tile[64][65];
    const int c0 = blockIdx.x * 64, r0 = blockIdx.y * 64;
    const int tx = threadIdx.x & 63, ty = threadIdx.x >> 6;   // ty 0..3
#pragma unroll
    for (int p = 0; p < 16; ++p) {
        const int r = p * 4 + ty;
        tile[r][tx] = in[(size_t)(r0 + r) * C + c0 + tx];
    }
    __syncthreads();
#pragma unroll
    for (int p = 0; p < 16; ++p) {
        const int c = p * 4 + ty;
        out[(size_t)(c0 + c) * R + r0 + tx] = (bf16_t)tile[tx][c];
    }
}

// bc[t] = sum_i b1[i] * W2[i][t]
__global__ void vecmat_kernel(const float* __restrict__ v, const float* __restrict__ W,
                              float* __restrict__ out) {
    const int t = blockIdx.x * blockDim.x + threadIdx.x;
    if (t >= 512) return;
    float s = 0.f;
    for (int i = 0; i < 512; ++i) s += v[i] * W[i * 512 + t];
    out[t] = s;
}

// c3[l][n] = sum_{m in seg l} chi[n,m]^2 ; also zeroes sbuf (replay-safe)
__global__ void c3_kernel(const float* __restrict__ chi, float* __restrict__ c3,
                          float* __restrict__ sbuf) {
    const int n = blockIdx.x * 256 + threadIdx.x;
    if (n >= NNODES) return;
    const float* ch = chi + (size_t)n * 15;
    float a = 0.f, b = 0.f, c = 0.f;
#pragma unroll
    for (int m = 0; m < 3; ++m)  a += ch[m] * ch[m];
#pragma unroll
    for (int m = 3; m < 8; ++m)  b += ch[m] * ch[m];
#pragma unroll
    for (int m = 8; m < 15; ++m) c += ch[m] * ch[m];
    c3[n] = a; c3[n + NNODES] = b; c3[n + 2 * NNODES] = c;
    sbuf[n] = 0.f;
}

// chbo[n,m] = chi[n,m] * s[n]
__global__ void chbo_kernel(const float* __restrict__ chi, const float* __restrict__ s,
                            float* __restrict__ chbo) {
    const int idx = blockIdx.x * 256 + threadIdx.x;
    if (idx >= NNODES * 15) return;
    chbo[idx] = chi[idx] * s[idx / 15];
}

extern "C" void kernel_launch(void* const* d_in, const int* in_sizes, int n_in,
                              void* d_out, int out_size, void* d_ws, size_t ws_size,
                              hipStream_t stream)
{
    const float* x   = (const float*)d_in[0];
    const float* chi = (const float*)d_in[1];
    // d_in[2] = z_one_hot : unused
    const float* W1  = (const float*)d_in[3];
    const float* b1  = (const float*)d_in[4];
    const float* W2  = (const float*)d_in[5];
    const float* W3  = (const float*)d_in[6];
    const float* W4  = (const float*)d_in[7];
    const float* b4  = (const float*)d_in[8];

    char* ws = (char*)d_ws;
    bf16_t* W1b  = (bf16_t*)(ws + 0);
    bf16_t* W4t  = (bf16_t*)(ws + 1048576);
    bf16_t* Wct  = (bf16_t*)(ws + 2621440);
    float*  bc   = (float*) (ws + 3145728);
    bf16_t* W2t  = (bf16_t*)(ws + 3147776);
    bf16_t* A3   = (bf16_t*)(ws + 3674112);
    float*  Wctp = (float*) (ws + 3674112);   // overlaps A3 head; dead before A3 written

    float*  xbo  = (float*)d_out;                          // 24576*512 f32
    float*  chbo = (float*)d_out + (size_t)NNODES * 512;   // 24576*15 f32
    char*   c0s  = (char*)d_out;
    float*  c3   = (float*) (c0s + 25165824);
    float*  sbuf = (float*) (c0s + 25460736);

    // prep (coalesced)
    prepw1_kernel<<<128, 256, 0, stream>>>(W1, W1b);
    tr_kernel<<<dim3(8, 8),  256, 0, stream>>>(W2, W2t, 512, 512);
    tr_kernel<<<dim3(8, 24), 256, 0, stream>>>(W4, W4t, 1536, 512);
    vecmat_kernel<<<2, 256, 0, stream>>>(b1, W2, bc);      // bc = b1 @ W2
    c3_kernel<<<96, 256, 0, stream>>>(chi, c3, sbuf);

    // Wct = (W1@W2)^T via split-K partials + reduce
    gemm8_kernel<<<dim3(2, 2, 4), 512, 0, stream>>>(W2t, W1b, Wctp, 512, 128, 512);
    wct_reduce_kernel<<<1024, 256, 0, stream>>>(Wctp, Wct);

    // G-GEMM (consumes f32 x directly): A3 = c_l * g^2 (coalesced) ; sbuf += g.W3
    gemm16x_kernel<<<dim3(128, 2), 1024, 0, stream>>>(x, Wct, bc, A3, W3, c3, sbuf);

    // chi_bo = chi * s
    chbo_kernel<<<1440, 256, 0, stream>>>(chi, sbuf, chbo);

    // x_bo = silu(A3 @ W4 + b4)
    gemm16_kernel<<<dim3(128, 2), 1024, 0, stream>>>(A3, W4t, b4, xbo, 512, 1536, 1);
}